// Round 1
// baseline (523.754 us; speedup 1.0000x reference)
//
#include <hip/hip_runtime.h>
#include <hip/hip_bf16.h>

#define B_ 2
#define L_ 2048
#define S_ 2048
#define H_ 8
#define E_ 64
#define D_ 64

typedef __attribute__((ext_vector_type(8))) short bf16x8;
typedef __attribute__((ext_vector_type(4))) float f32x4;

__device__ __forceinline__ short f2bf(float f) {
    unsigned u = __builtin_bit_cast(unsigned, f);
    u = (u + 0x7fffu + ((u >> 16) & 1u)) >> 16;
    return (short)u;
}

__global__ __launch_bounds__(256, 2)
void dual_attn(const float* __restrict__ Q, const float* __restrict__ K,
               const float* __restrict__ VD, const float* __restrict__ VW,
               const float* __restrict__ FG, float* __restrict__ out,
               float* __restrict__ regacc)
{
    // grid = 512 blocks: bh-major (bh = wg>>5, qtile = wg&31), bijective XCD swizzle
    int bid = blockIdx.x;
    int wg  = (bid & 7) * 64 + (bid >> 3);   // 512/8 = 64 per XCD -> 2 bh-groups per XCD L2
    int bh  = wg >> 5;
    int qt  = wg & 31;
    int b = bh >> 3, h = bh & 7;

    int tid  = threadIdx.x;
    int wid  = tid >> 6;
    int lane = tid & 63;
    int g = lane >> 4;     // 16-lane group 0..3
    int c = lane & 15;     // col-in-16

    int q0 = qt * 64 + wid * 16;   // this wave's 16 q-rows

    __shared__ __align__(16) short plds[4][2][16][40];   // [wave][path][qrow][s padded 32->40]

    // ---- Q fragments (A operand) + row squared-norms ----
    bf16x8 a_frag[2];
    float qn2 = 0.f;
    {
        const float* qp = Q + (((b * L_ + q0 + c) * H_ + h) * E_) + g * 8;
#pragma unroll
        for (int kk = 0; kk < 2; kk++) {
            const float4* p4 = (const float4*)(qp + kk * 32);
            float4 x0 = p4[0], x1 = p4[1];
            float v[8] = {x0.x, x0.y, x0.z, x0.w, x1.x, x1.y, x1.z, x1.w};
#pragma unroll
            for (int j = 0; j < 8; j++) { qn2 += v[j] * v[j]; a_frag[kk][j] = f2bf(v[j]); }
        }
        qn2 += __shfl_xor(qn2, 16);
        qn2 += __shfl_xor(qn2, 32);
    }
    // redistribute qn2 to C-layout rows (row = 4g+r)
    float qn2c[4];
#pragma unroll
    for (int r = 0; r < 4; r++) qn2c[r] = __shfl(qn2, g * 4 + r);

    // ---- accumulators ----
    f32x4 zero4 = {0.f, 0.f, 0.f, 0.f};
    f32x4 o_d[4] = {zero4, zero4, zero4, zero4};
    f32x4 o_w[4] = {zero4, zero4, zero4, zero4};
    float m_d[4], m_w[4], l_d[4], l_w[4];
#pragma unroll
    for (int r = 0; r < 4; r++) { m_d[r] = -1e30f; m_w[r] = -1e30f; l_d[r] = 0.f; l_w[r] = 0.f; }

    float regsum = 0.f;
    const float scale = 0.125f;

#pragma unroll 1
    for (int s0 = 0; s0 < S_; s0 += 32) {
        // ---- K fragments (B operand) + col squared-norms ----
        bf16x8 b_frag[2][2];
        float kn2[2];
#pragma unroll
        for (int nt = 0; nt < 2; nt++) {
            const float* kp = K + (((b * S_ + s0 + nt * 16 + c) * H_ + h) * E_) + g * 8;
            float acc = 0.f;
#pragma unroll
            for (int kk = 0; kk < 2; kk++) {
                const float4* p4 = (const float4*)(kp + kk * 32);
                float4 x0 = p4[0], x1 = p4[1];
                float v[8] = {x0.x, x0.y, x0.z, x0.w, x1.x, x1.y, x1.z, x1.w};
#pragma unroll
                for (int j = 0; j < 8; j++) { acc += v[j] * v[j]; b_frag[nt][kk][j] = f2bf(v[j]); }
            }
            acc += __shfl_xor(acc, 16);
            acc += __shfl_xor(acc, 32);
            kn2[nt] = acc;
        }

        // ---- QK^T (raw dot scores), C layout: row=4g+r, col=c ----
        f32x4 cd0 = __builtin_amdgcn_mfma_f32_16x16x32_bf16(a_frag[0], b_frag[0][0], zero4, 0, 0, 0);
        cd0 = __builtin_amdgcn_mfma_f32_16x16x32_bf16(a_frag[1], b_frag[0][1], cd0, 0, 0, 0);
        f32x4 cd1 = __builtin_amdgcn_mfma_f32_16x16x32_bf16(a_frag[0], b_frag[1][0], zero4, 0, 0, 0);
        cd1 = __builtin_amdgcn_mfma_f32_16x16x32_bf16(a_frag[1], b_frag[1][1], cd1, 0, 0, 0);

        // ---- wedge scores, scaling, reg accumulation ----
        float ds0[4], ds1[4], ws0[4], ws1[4];
#pragma unroll
        for (int r = 0; r < 4; r++) {
            float d0 = cd0[r], d1 = cd1[r];
            float w0 = sqrtf(fmaxf(qn2c[r] * kn2[0] - d0 * d0, 0.f) + 1e-8f) * scale;
            float w1 = sqrtf(fmaxf(qn2c[r] * kn2[1] - d1 * d1, 0.f) + 1e-8f) * scale;
            d0 *= scale; d1 *= scale;
            regsum += fabsf(d0) + fabsf(d1) + w0 + w1;
            ds0[r] = d0; ds1[r] = d1; ws0[r] = w0; ws1[r] = w1;
        }

        // ---- online softmax update, both paths ----
        float pd0[4], pd1[4], pw0[4], pw1[4];
#pragma unroll
        for (int r = 0; r < 4; r++) {
            float md = fmaxf(ds0[r], ds1[r]);
            float mw = fmaxf(ws0[r], ws1[r]);
#pragma unroll
            for (int off = 1; off < 16; off <<= 1) {
                md = fmaxf(md, __shfl_xor(md, off));
                mw = fmaxf(mw, __shfl_xor(mw, off));
            }
            float mnd = fmaxf(m_d[r], md);
            float mnw = fmaxf(m_w[r], mw);
            float ad = __expf(m_d[r] - mnd);
            float aw = __expf(m_w[r] - mnw);
            m_d[r] = mnd; m_w[r] = mnw;
            pd0[r] = __expf(ds0[r] - mnd); pd1[r] = __expf(ds1[r] - mnd);
            pw0[r] = __expf(ws0[r] - mnw); pw1[r] = __expf(ws1[r] - mnw);
            float rsd = pd0[r] + pd1[r];
            float rsw = pw0[r] + pw1[r];
#pragma unroll
            for (int off = 1; off < 16; off <<= 1) {
                rsd += __shfl_xor(rsd, off);
                rsw += __shfl_xor(rsw, off);
            }
            l_d[r] = l_d[r] * ad + rsd;
            l_w[r] = l_w[r] * aw + rsw;
#pragma unroll
            for (int dt = 0; dt < 4; dt++) { o_d[dt][r] *= ad; o_w[dt][r] *= aw; }
        }

        // ---- transpose P (C layout -> A fragment layout) via per-wave LDS ----
#pragma unroll
        for (int r = 0; r < 4; r++) {
            plds[wid][0][4 * g + r][c]      = f2bf(pd0[r]);
            plds[wid][0][4 * g + r][16 + c] = f2bf(pd1[r]);
            plds[wid][1][4 * g + r][c]      = f2bf(pw0[r]);
            plds[wid][1][4 * g + r][16 + c] = f2bf(pw1[r]);
        }
        bf16x8 pa_d = *(const bf16x8*)&plds[wid][0][c][g * 8];
        bf16x8 pa_w = *(const bf16x8*)&plds[wid][1][c][g * 8];

        // ---- V fragments (B operand) + PV MFMAs ----
        const float* vdp = VD + (((b * S_ + s0 + g * 8) * H_ + h) * D_) + c;
        const float* vwp = VW + (((b * S_ + s0 + g * 8) * H_ + h) * D_) + c;
#pragma unroll
        for (int dt = 0; dt < 4; dt++) {
            bf16x8 vf_d, vf_w;
#pragma unroll
            for (int j = 0; j < 8; j++) {
                vf_d[j] = f2bf(vdp[j * (H_ * D_) + dt * 16]);
                vf_w[j] = f2bf(vwp[j * (H_ * D_) + dt * 16]);
            }
            o_d[dt] = __builtin_amdgcn_mfma_f32_16x16x32_bf16(pa_d, vf_d, o_d[dt], 0, 0, 0);
            o_w[dt] = __builtin_amdgcn_mfma_f32_16x16x32_bf16(pa_w, vf_w, o_w[dt], 0, 0, 0);
        }
    }

    // ---- epilogue: normalize, gate-blend, store ----
    float fgv = FG[0];
    float gate = 1.f / (1.f + __expf(-fgv));
    float omg = 1.f - gate;
#pragma unroll
    for (int r = 0; r < 4; r++) {
        float ild = 1.f / l_d[r], ilw = 1.f / l_w[r];
        int qq = q0 + 4 * g + r;
        float* op = out + ((b * L_ + qq) * H_ + h) * D_;
#pragma unroll
        for (int dt = 0; dt < 4; dt++) {
            op[dt * 16 + c] = omg * o_d[dt][r] * ild + gate * o_w[dt][r] * ilw;
        }
    }

    // ---- attn_reg partial: wave reduce + one atomic ----
#pragma unroll
    for (int off = 1; off < 64; off <<= 1) regsum += __shfl_xor(regsum, off);
    if (lane == 0) atomicAdd(regacc, regsum);
}

__global__ void finalize_reg(const float* __restrict__ regacc, float* __restrict__ out)
{
    // reg = (sum|dot_s| + sum|wedge_s|) / (2 * B*H*L*S)
    out[B_ * L_ * H_ * D_] = regacc[0] * (1.0f / 134217728.0f);
}

extern "C" void kernel_launch(void* const* d_in, const int* in_sizes, int n_in,
                              void* d_out, int out_size, void* d_ws, size_t ws_size,
                              hipStream_t stream)
{
    const float* Q  = (const float*)d_in[0];
    const float* K  = (const float*)d_in[1];
    const float* VD = (const float*)d_in[2];
    const float* VW = (const float*)d_in[3];
    const float* FG = (const float*)d_in[4];
    float* out = (float*)d_out;
    float* regacc = (float*)d_ws;

    hipMemsetAsync(regacc, 0, sizeof(float), stream);
    dual_attn<<<dim3(512), dim3(256), 0, stream>>>(Q, K, VD, VW, FG, out, regacc);
    finalize_reg<<<1, 1, 0, stream>>>(regacc, out);
}

// Round 2
// 287.652 us; speedup vs baseline: 1.8208x; 1.8208x over previous
//
#include <hip/hip_runtime.h>
#include <hip/hip_bf16.h>

#define B_ 2
#define L_ 2048
#define S_ 2048
#define H_ 8
#define E_ 64
#define D_ 64

typedef __attribute__((ext_vector_type(8))) short bf16x8;
typedef __attribute__((ext_vector_type(4))) float f32x4;

__device__ __forceinline__ short f2bf(float f) {
    unsigned u = __builtin_bit_cast(unsigned, f);
    u = (u + 0x7fffu + ((u >> 16) & 1u)) >> 16;
    return (short)u;
}

// ---- prep: K[b][s][h][e] f32 -> Kb[bh][s][e] bf16, kn2[bh][s] f32 ----
__global__ __launch_bounds__(256)
void prep_k(const float* __restrict__ K, short* __restrict__ Kb, float* __restrict__ kn2)
{
    int t = threadIdx.x;
    int r = t >> 4, te = t & 15;
    int rowid = blockIdx.x * 16 + r;          // rowid = bh*S + s
    int bh = rowid >> 11, s = rowid & 2047;
    int b = bh >> 3, h = bh & 7;
    const float4* src = (const float4*)(K + (((size_t)b * S_ + s) * H_ + h) * E_) + te;
    float4 x = *src;
    float sq = x.x * x.x + x.y * x.y + x.z * x.z + x.w * x.w;
#pragma unroll
    for (int off = 1; off < 16; off <<= 1) sq += __shfl_xor(sq, off);
    short4 o;
    o.x = f2bf(x.x); o.y = f2bf(x.y); o.z = f2bf(x.z); o.w = f2bf(x.w);
    *(short4*)(Kb + (size_t)rowid * 64 + te * 4) = o;
    if (te == 0) kn2[rowid] = sq;
}

// ---- prep: V[b][s][h][d] f32 -> Vb[bh][d][s] bf16 (transposed) ----
__global__ __launch_bounds__(256)
void prep_v(const float* __restrict__ V, short* __restrict__ Vb)
{
    int blk = blockIdx.x;                     // (bh)*32 + st
    int st = blk & 31, bh = blk >> 5;
    int b = bh >> 3, h = bh & 7;
    int s0 = st * 64;
    __shared__ short tile[64][72];
    int t = threadIdx.x;
    {
        int i = t >> 2, q = t & 3;            // s-row, quarter of d
        const float4* s4 = (const float4*)(V + (((size_t)b * S_ + s0 + i) * H_ + h) * D_ + q * 16);
#pragma unroll
        for (int j = 0; j < 4; j++) {
            float4 x = s4[j];
            int d = q * 16 + j * 4;
            short4 o;
            o.x = f2bf(x.x); o.y = f2bf(x.y); o.z = f2bf(x.z); o.w = f2bf(x.w);
            *(short4*)&tile[i][d] = o;
        }
    }
    __syncthreads();
    {
        int d = t >> 2, q = t & 3;            // d-row, quarter of s
        short v16[16];
#pragma unroll
        for (int k = 0; k < 16; k++) v16[k] = tile[q * 16 + k][d];
        short* dst = Vb + ((size_t)bh * 64 + d) * S_ + s0 + q * 16;
        ((int4*)dst)[0] = ((int4*)v16)[0];
        ((int4*)dst)[1] = ((int4*)v16)[1];
    }
}

__global__ __launch_bounds__(256, 2)
void dual_attn(const float* __restrict__ Q, const short* __restrict__ Kb,
               const float* __restrict__ kn2g, const short* __restrict__ VbD,
               const short* __restrict__ VbW, const float* __restrict__ FG,
               float* __restrict__ out, float* __restrict__ regacc)
{
    int bid = blockIdx.x;
    int wg  = (bid & 7) * 64 + (bid >> 3);    // bijective XCD swizzle (512 = 8*64)
    int bh  = wg >> 5;
    int qt  = wg & 31;
    int b = bh >> 3, h = bh & 7;

    int tid  = threadIdx.x;
    int wid  = tid >> 6;
    int lane = tid & 63;
    int g = lane >> 4;
    int c = lane & 15;

    int q0 = qt * 64 + wid * 16;

    __shared__ __align__(16) short plds[4][2][16][40];

    // ---- Q fragments (A operand, f32 source) + row squared-norms ----
    bf16x8 a_frag[2];
    float qn2 = 0.f;
    {
        const float* qp = Q + (((size_t)b * L_ + q0 + c) * H_ + h) * E_ + g * 8;
#pragma unroll
        for (int kk = 0; kk < 2; kk++) {
            const float4* p4 = (const float4*)(qp + kk * 32);
            float4 x0 = p4[0], x1 = p4[1];
            float v[8] = {x0.x, x0.y, x0.z, x0.w, x1.x, x1.y, x1.z, x1.w};
#pragma unroll
            for (int j = 0; j < 8; j++) { qn2 += v[j] * v[j]; a_frag[kk][j] = f2bf(v[j]); }
        }
        qn2 += __shfl_xor(qn2, 16);
        qn2 += __shfl_xor(qn2, 32);
    }
    float qn2c[4];
#pragma unroll
    for (int r = 0; r < 4; r++) qn2c[r] = __shfl(qn2, g * 4 + r);

    f32x4 zero4 = {0.f, 0.f, 0.f, 0.f};
    f32x4 o_d[4] = {zero4, zero4, zero4, zero4};
    f32x4 o_w[4] = {zero4, zero4, zero4, zero4};
    float lacc_d[4] = {0.f, 0.f, 0.f, 0.f};
    float lacc_w[4] = {0.f, 0.f, 0.f, 0.f};
    float regsum = 0.f;
    const float scale = 0.125f;
    const float MD = 8.0f, MW = 16.0f;   // fixed softmax shifts (Cauchy-Schwarz-safe)

    const short* kbl  = Kb   + (size_t)bh * (S_ * 64) + c * 64 + g * 8;
    const float* kn2l = kn2g + (size_t)bh * S_ + c;
    const short* vdl  = VbD  + (size_t)bh * (64 * S_) + c * S_ + g * 8;
    const short* vwl  = VbW  + (size_t)bh * (64 * S_) + c * S_ + g * 8;

#pragma unroll 2
    for (int s0 = 0; s0 < S_; s0 += 32) {
        // K fragments: 16B vector loads from prepped bf16
        bf16x8 bf00 = *(const bf16x8*)(kbl + (size_t)(s0 +  0) * 64);
        bf16x8 bf01 = *(const bf16x8*)(kbl + (size_t)(s0 +  0) * 64 + 32);
        bf16x8 bf10 = *(const bf16x8*)(kbl + (size_t)(s0 + 16) * 64);
        bf16x8 bf11 = *(const bf16x8*)(kbl + (size_t)(s0 + 16) * 64 + 32);
        float kn20 = kn2l[s0], kn21 = kn2l[s0 + 16];

        f32x4 cd0 = __builtin_amdgcn_mfma_f32_16x16x32_bf16(a_frag[0], bf00, zero4, 0, 0, 0);
        cd0 = __builtin_amdgcn_mfma_f32_16x16x32_bf16(a_frag[1], bf01, cd0, 0, 0, 0);
        f32x4 cd1 = __builtin_amdgcn_mfma_f32_16x16x32_bf16(a_frag[0], bf10, zero4, 0, 0, 0);
        cd1 = __builtin_amdgcn_mfma_f32_16x16x32_bf16(a_frag[1], bf11, cd1, 0, 0, 0);

        // wedge + scale + reg + fixed-M exp; l accumulates lane-locally
        float pd0[4], pd1[4], pw0[4], pw1[4];
#pragma unroll
        for (int r = 0; r < 4; r++) {
            float d0 = cd0[r], d1 = cd1[r];
            float w0 = sqrtf(fmaxf(qn2c[r] * kn20 - d0 * d0, 0.f) + 1e-8f) * scale;
            float w1 = sqrtf(fmaxf(qn2c[r] * kn21 - d1 * d1, 0.f) + 1e-8f) * scale;
            d0 *= scale; d1 *= scale;
            regsum += fabsf(d0) + fabsf(d1) + w0 + w1;
            pd0[r] = __expf(d0 - MD); pd1[r] = __expf(d1 - MD);
            pw0[r] = __expf(w0 - MW); pw1[r] = __expf(w1 - MW);
            lacc_d[r] += pd0[r] + pd1[r];
            lacc_w[r] += pw0[r] + pw1[r];
        }

        // P transpose (C layout -> A fragment layout) via per-wave LDS
#pragma unroll
        for (int r = 0; r < 4; r++) {
            plds[wid][0][4 * g + r][c]      = f2bf(pd0[r]);
            plds[wid][0][4 * g + r][16 + c] = f2bf(pd1[r]);
            plds[wid][1][4 * g + r][c]      = f2bf(pw0[r]);
            plds[wid][1][4 * g + r][16 + c] = f2bf(pw1[r]);
        }
        bf16x8 pa_d = *(const bf16x8*)&plds[wid][0][c][g * 8];
        bf16x8 pa_w = *(const bf16x8*)&plds[wid][1][c][g * 8];

        // V fragments: 16B vector loads from transposed bf16; PV MFMAs
#pragma unroll
        for (int dt = 0; dt < 4; dt++) {
            bf16x8 vf_d = *(const bf16x8*)(vdl + (size_t)dt * 16 * S_ + s0);
            bf16x8 vf_w = *(const bf16x8*)(vwl + (size_t)dt * 16 * S_ + s0);
            o_d[dt] = __builtin_amdgcn_mfma_f32_16x16x32_bf16(pa_d, vf_d, o_d[dt], 0, 0, 0);
            o_w[dt] = __builtin_amdgcn_mfma_f32_16x16x32_bf16(pa_w, vf_w, o_w[dt], 0, 0, 0);
        }
    }

    // ---- epilogue: reduce l across the 16-col groups (once), blend, store ----
#pragma unroll
    for (int r = 0; r < 4; r++) {
#pragma unroll
        for (int off = 1; off < 16; off <<= 1) {
            lacc_d[r] += __shfl_xor(lacc_d[r], off);
            lacc_w[r] += __shfl_xor(lacc_w[r], off);
        }
    }
    float fgv  = FG[0];
    float gate = 1.f / (1.f + __expf(-fgv));
    float omg  = 1.f - gate;
#pragma unroll
    for (int r = 0; r < 4; r++) {
        float ild = 1.f / lacc_d[r], ilw = 1.f / lacc_w[r];
        int qq = q0 + 4 * g + r;
        float* op = out + (((size_t)b * L_ + qq) * H_ + h) * D_;
#pragma unroll
        for (int dt = 0; dt < 4; dt++) {
            op[dt * 16 + c] = omg * o_d[dt][r] * ild + gate * o_w[dt][r] * ilw;
        }
    }

#pragma unroll
    for (int off = 1; off < 64; off <<= 1) regsum += __shfl_xor(regsum, off);
    if (lane == 0) atomicAdd(regacc, regsum);
}

__global__ void finalize_reg(const float* __restrict__ regacc, float* __restrict__ out)
{
    out[B_ * L_ * H_ * D_] = regacc[0] * (1.0f / 134217728.0f);
}

extern "C" void kernel_launch(void* const* d_in, const int* in_sizes, int n_in,
                              void* d_out, int out_size, void* d_ws, size_t ws_size,
                              hipStream_t stream)
{
    const float* Q  = (const float*)d_in[0];
    const float* K  = (const float*)d_in[1];
    const float* VD = (const float*)d_in[2];
    const float* VW = (const float*)d_in[3];
    const float* FG = (const float*)d_in[4];
    float* out = (float*)d_out;

    char* ws = (char*)d_ws;
    float* regacc = (float*)ws;                                  // 4 B
    float* kn2    = (float*)(ws + 256);                          // 128 KiB
    short* Kb     = (short*)(ws + 256 + 131072);                 // 4 MiB
    short* VbD    = (short*)(ws + 256 + 131072 + 4194304);       // 4 MiB
    short* VbW    = (short*)(ws + 256 + 131072 + 8388608);       // 4 MiB

    hipMemsetAsync(regacc, 0, sizeof(float), stream);
    prep_k<<<dim3(2048), dim3(256), 0, stream>>>(K, Kb, kn2);
    prep_v<<<dim3(512), dim3(256), 0, stream>>>(VD, VbD);
    prep_v<<<dim3(512), dim3(256), 0, stream>>>(VW, VbW);
    dual_attn<<<dim3(512), dim3(256), 0, stream>>>(Q, Kb, kn2, VbD, VbW, FG, out, regacc);
    finalize_reg<<<1, 1, 0, stream>>>(regacc, out);
}